// Round 3
// baseline (98.277 us; speedup 1.0000x reference)
//
#include <hip/hip_runtime.h>
#include <math.h>

#define NT_ 365
#define NS_ 1024
#define NH_ 64
#define NG_ 32
#define NW_ 514        // NH*8 + 2
#define CH_ 64         // timesteps per chunk (= wave size)
#define NCHUNK_ 6      // ceil(365/64); tail steps are harmless dummies
#define YPAD_ 65       // padded row stride: bank = (lane+j)%32, conflict-free R/W
#define SUB_ 8         // met sub-chunk: register double-buffer depth
#define WB_ 8          // waves (= sites) per block: 2 waves/SIMD on active CUs

__device__ __forceinline__ float sigmoidf(float v) {
  return 1.0f / (1.0f + expf(-v));
}

// met = (Ps, Pl, relu(Ta), E); relu folded here since gm > 0
__device__ __forceinline__ float4 compute_met(float4 xv) {
  const float P = xv.x, E = xv.y, T1 = xv.z, T2 = xv.w;
  const float Ta = (T1 + T2) * 0.5f;
  float rP;
  if (T2 <= 0.0f) {
    rP = 0.0f;
  } else if (T1 >= 0.0f) {
    rP = 1.0f;
  } else {
    float r = (T1 + T2) / (T2 - T1);
    r = fminf(fmaxf(r, -0.999999f), 0.999999f);
    rP = 1.0f - acosf(r) * (1.0f / 3.1415f);
  }
  float4 m;
  m.x = (1.0f - rP) * P;   // Ps
  m.y = rP * P;            // Pl
  m.z = fmaxf(Ta, 0.0f);   // relu(Ta)
  m.w = E;
  return m;
}

// WAVE-PACKING round: the R2 null (chain 9->4 ops, zero time change) falsified
// the dep-latency theory. Model now: ~296 cyc/step of which only ~72 are VALU
// issue (18 inst x ~4 cyc solo cadence) -- with 1 wave/SIMD the remaining
// ~224 cyc/step are dead SIMD cycles no one can fill. Fix: pack 8 sites per
// block (512 thr) -> 141 KB LDS -> 1 block/CU -> 2 waves/SIMD on 128 CUs.
// Two independent serial chains interleave on each SIMD; each fills the
// other's stall/cadence gaps. Algorithm is byte-identical to R2.
__global__ __launch_bounds__(512, 2) void waternet_scan(
    const float* __restrict__ x,     // [NT, NS, 4]
    const float* __restrict__ xc,    // [NS, NG]
    const float* __restrict__ fc_w,  // [NW, NG]
    const float* __restrict__ fc_b,  // [NW]
    float* __restrict__ out)         // [NT, NS]
{
  __shared__ float4 smet[WB_][CH_];          // 8 KB:   [wave][step] met
  __shared__ float  ytile[WB_][CH_ * YPAD_]; // 133 KB: per-wave y rows

  const int tid  = threadIdx.x;
  const int lane = tid & 63;
  const int wv   = tid >> 6;
  const int site = blockIdx.x * WB_ + wv;
  const int us   = __builtin_amdgcn_readfirstlane(site);
  const float4* xp = (const float4*)x;

  // chunk-0 prefetch first: HBM latency hides under the gate GEMM
  float4 xcur = xp[lane * NS_ + site];  // t = lane

  // ---- prologue GEMM: w[site, j] = xc[site,:] . fc_w[j,:] + fc_b[j]
  float acc[8];
#pragma unroll
  for (int k = 0; k < 8; ++k) acc[k] = fc_b[k * NH_ + lane];
  float accq = fc_b[NW_ - 1];

  const float4* xcq = (const float4*)(xc + us * NG_);
  const float4* wq4 = (const float4*)fc_w;
#pragma unroll
  for (int g4 = 0; g4 < NG_ / 4; ++g4) {
    const float4 xv = xcq[g4];
#pragma unroll
    for (int k = 0; k < 8; ++k) {
      const float4 w = wq4[(k * NH_ + lane) * (NG_ / 4) + g4];
      acc[k] = fmaf(xv.x, w.x, acc[k]);
      acc[k] = fmaf(xv.y, w.y, acc[k]);
      acc[k] = fmaf(xv.z, w.z, acc[k]);
      acc[k] = fmaf(xv.w, w.w, acc[k]);
    }
    {
      const float4 w = wq4[(NW_ - 1) * (NG_ / 4) + g4];
      accq = fmaf(xv.x, w.x, accq);
      accq = fmaf(xv.y, w.y, accq);
      accq = fmaf(xv.z, w.z, accq);
      accq = fmaf(xv.w, w.w, accq);
    }
  }

  // ---- gates (per-lane = per hidden unit)
  const float gm = expf(acc[0]) + 1.0f;
  const float ge = sigmoidf(acc[1]) * 2.0f;
  const float go = sigmoidf(acc[2]);
  const float gl = expf(acc[3] * 2.0f);
  float mx = acc[4];
#pragma unroll
  for (int mm = 32; mm >= 1; mm >>= 1) mx = fmaxf(mx, __shfl_xor(mx, mm, 64));
  const float ex = expf(acc[4] - mx);
  float sm = ex;
#pragma unroll
  for (int mm = 32; mm >= 1; mm >>= 1) sm += __shfl_xor(sm, mm, 64);
  const float ga = ex / sm;
  const float gb = sigmoidf(acc[5]);
  const float kb = sigmoidf(acc[6]) * 0.1f;
  const float gi = sigmoidf(acc[7]);
  const float qb = fmaxf(accq, 0.0f) * (1.0f / NH_);
  const float kb1m = 1.0f - kb;                 // G' = kb1m*G + gbgo*M
  const float nge  = -ge;
  const float gq1  = go * (1.0f - gb) - 1.0f;   // y = ga*(H + M*gq1 + G*kb)
  const float omg  = 1.0f - go;                 // H*(1-go)   branch of H0'
  const float gogl = go * gl;                   // H - go*gl  branch of H0'
  const float gbgo = gb * go;                   // G feed: gb*Q2a = gbgo*M

  // ---- scan state (dSm is the 1-step-ahead pipelined snow/forcing term)
  float S0 = 0.0f, H0 = 0.0f, G = 0.0f, dSm = 0.0f;

  // stage chunk-0 met (lane = step); per-wave slice + in-order DS -> no barrier
  smet[wv][lane] = compute_met(xcur);

  // advances the S-chain for met index t and produces dSm_t from S0_{t-1}.
  // Called exactly once per timestep: chunk-top for local step 0, then each
  // h_step pre-stages the NEXT step. Off the H critical path (S-chain depth 3).
  auto s_stage = [&](const float4 m) {
    const float melt = m.z * gm;          // relu(Ta)*gm
    const float Sm   = fminf(S0, melt);
    const float e1   = fmaf(m.w, nge, Sm);   // Sm - E*ge
    dSm = fmaf(m.y, gi, e1);                 // + Pl*gi
    S0  = (S0 - Sm) + m.x;                   // + Ps
  };

  // recurrent path: z -> {omg*z, z-gogl} -> max3 -> min  (4 dependent ops)
  auto h_step = [&](float* ywaddr) {
    const float z = H0 + dSm;
    const float a = z * omg;
    const float b = z - gogl;
    H0 = fminf(fmaxf(fmaxf(a, b), 0.0f), gl);   // v_max3_f32 + v_min_f32
    const float Hh = fmaxf(z, 0.0f);
    const float M  = fminf(Hh, gl);
    G = fmaf(kb1m, G, gbgo * M);                // G_t = kb1m*G + gb*go*M
    *ywaddr = ga * fmaf(kb, G, fmaf(gq1, M, Hh));
  };

  float*       yw = &ytile[wv][lane];          // step j writes yw[j*YPAD_]
  const float* yr = &ytile[wv][lane * YPAD_];  // reduce: lane sums its row

#pragma unroll 1   // keep body I-cache resident across 6 iterations
  for (int c = 0; c < NCHUNK_; ++c) {
    // prefetch chunk c+1 from HBM (clamped dummy tail) — in flight all chunk
    int tn = (c + 1) * CH_ + lane;
    tn = (tn < NT_) ? tn : (NT_ - 1);
    const float4 xnext = xp[tn * NS_ + site];

    const float4* mp = &smet[wv][0];

    // ---- 8-step register double-buffer: loads for sub-chunk k+1 issue
    // before sub-chunk k's compute -> ds_read latency fully covered.
    float4 mb0[SUB_], mb1[SUB_];
#pragma unroll
    for (int u = 0; u < SUB_; ++u) mb0[u] = mp[u];

    // pipeline fill: dSm/S0 for this chunk's first step (met local index 0)
    s_stage(mb0[0]);

#pragma unroll
    for (int sc = 0; sc < CH_ / SUB_; ++sc) {
      float4*       cur = (sc & 1) ? mb1 : mb0;
      float4*       nxt = (sc & 1) ? mb0 : mb1;
      if (sc < CH_ / SUB_ - 1) {
#pragma unroll
        for (int u = 0; u < SUB_; ++u) nxt[u] = mp[SUB_ * (sc + 1) + u];
      }
#pragma unroll
      for (int u = 0; u < SUB_; ++u) {
        h_step(yw + (SUB_ * sc + u) * YPAD_);
        // pre-stage NEXT step's dSm/S0 (met local index 8*sc+u+1);
        // the chunk's last step defers to the next chunk-top s_stage.
        if (u < SUB_ - 1)                     s_stage(cur[u + 1]);
        else if (sc < CH_ / SUB_ - 1)         s_stage(nxt[0]);
      }
    }

    // ---- transposed reduction: lane t' sums row t' (bank=(t'+h)%32, free)
    float r0 = 0.0f, r1 = 0.0f, r2 = 0.0f, r3 = 0.0f;
#pragma unroll
    for (int h = 0; h < CH_; h += 4) {
      r0 += yr[h + 0];
      r1 += yr[h + 1];
      r2 += yr[h + 2];
      r3 += yr[h + 3];
    }
    const int t_out = c * CH_ + lane;
    if (t_out < NT_) out[t_out * NS_ + site] = ((r0 + r1) + (r2 + r3)) + qb;

    // stage next chunk's met (reads above already issued -> in-order safe)
    if (c + 1 < NCHUNK_) smet[wv][lane] = compute_met(xnext);
  }
}

extern "C" void kernel_launch(void* const* d_in, const int* in_sizes, int n_in,
                              void* d_out, int out_size, void* d_ws, size_t ws_size,
                              hipStream_t stream) {
  const float* x    = (const float*)d_in[0];
  const float* xc   = (const float*)d_in[1];
  const float* fc_w = (const float*)d_in[2];
  const float* fc_b = (const float*)d_in[3];
  float* out = (float*)d_out;

  // 1024 sites, 8 sites (waves) per block -> 128 blocks; 141 KB LDS forces
  // 1 block/CU -> 2 waves/SIMD on 128 active CUs (vs 1 wave/SIMD before):
  // two independent serial chains per SIMD fill each other's stall slots.
  hipLaunchKernelGGL(waternet_scan, dim3(NS_ / WB_), dim3(WB_ * 64), 0, stream,
                     x, xc, fc_w, fc_b, out);
}

// Round 4
// 93.341 us; speedup vs baseline: 1.0529x; 1.0529x over previous
//
#include <hip/hip_runtime.h>
#include <math.h>

#define NT_ 365
#define NS_ 1024
#define NH_ 64
#define NG_ 32
#define NW_ 514        // NH*8 + 2
#define CH_ 64         // timesteps per chunk
#define PH_ 32         // timesteps per phase (half chunk)
#define YPAD_ 65       // padded ytile row stride: conflict-free R/W

__device__ __forceinline__ float sigmoidf(float v) {
  return 1.0f / (1.0f + expf(-v));
}

// broadcast one lane's float to all lanes via SGPR (uniform lane index)
__device__ __forceinline__ float rdl(float v, int l) {
  return __int_as_float(__builtin_amdgcn_readlane(__float_as_int(v), l));
}

// met = (Ps, Pl, relu(Ta), E); relu folded here since gm > 0
__device__ __forceinline__ float4 compute_met(float4 xv) {
  const float P = xv.x, E = xv.y, T1 = xv.z, T2 = xv.w;
  const float Ta = (T1 + T2) * 0.5f;
  float rP;
  if (T2 <= 0.0f) {
    rP = 0.0f;
  } else if (T1 >= 0.0f) {
    rP = 1.0f;
  } else {
    float r = (T1 + T2) / (T2 - T1);
    r = fminf(fmaxf(r, -0.999999f), 0.999999f);
    rP = 1.0f - acosf(r) * (1.0f / 3.1415f);
  }
  float4 m;
  m.x = (1.0f - rP) * P;   // Ps
  m.y = rP * P;            // Pl
  m.z = fmaxf(Ta, 0.0f);   // relu(Ta)
  m.w = E;
  return m;
}

// PRODUCER/CONSUMER WAVE-SPLIT. R3 showed per-wave duration is invariant to
// co-residency (2 waves/SIMD interleave for free): the wall is the per-wave
// in-order instruction-stream walk (~275 cyc/step for ~20 slots/step). So the
// lever is stream length per wave. Each site gets TWO waves:
//   S-wave: snow chain only -> dSm[t][h] into LDS   (~12 slots/step)
//   H-wave: H/G/y chain only, consuming dSm          (~12 slots/step)
// Met reaches the S-wave via v_readlane from per-lane registers (lane = t),
// killing smet and the old pointer-select double-buffer (scratch suspect).
// Double-buffered 32-step phases, S one phase ahead, 12 barriers total.
__global__ __launch_bounds__(512) void waternet_scan(
    const float* __restrict__ x,     // [NT, NS, 4]
    const float* __restrict__ xc,    // [NS, NG]
    const float* __restrict__ fc_w,  // [NW, NG]
    const float* __restrict__ fc_b,  // [NW]
    float* __restrict__ out)         // [NT, NS]
{
  __shared__ float dsm[2][4][PH_][NH_];    // 64 KB: dbuf x site x step x h
  __shared__ float ytile[4][CH_ * YPAD_];  // 66.6 KB: per-site y rows

  const int tid  = threadIdx.x;
  const int lane = tid & 63;
  const int wv   = tid >> 6;
  const int myv  = wv & 3;          // site slot within block
  const bool isS = (wv >= 4);       // waves 4..7 = S-producers for sites 0..3
  const int site = (blockIdx.x << 2) + myv;
  const int us   = __builtin_amdgcn_readfirstlane(site);
  const float4* xp  = (const float4*)x;
  const float4* xcq = (const float4*)(xc + us * NG_);
  const float4* wq4 = (const float4*)fc_w;

  // role-specific state (declared for both so lambdas capture cleanly)
  float gm = 0.f, nge = 0.f, gi = 0.f;                       // S gates
  float gl = 0.f, mgo = 0.f, kb1m = 0.f, gbgo = 0.f;         // H gates
  float ga = 0.f, c1 = 0.f, c2 = 0.f, qb = 0.f;
  float4 mm    = make_float4(0.f, 0.f, 0.f, 0.f);            // met regs, lane=t
  float4 xnext = make_float4(0.f, 0.f, 0.f, 0.f);
  float S0 = 0.f, H0 = 0.f, G = 0.f;

  if (isS) {
    // ---- S prologue: x loads first (latency under GEMM), 3-row mini-GEMM
    const float4 xcur = xp[lane * NS_ + site];            // chunk 0, t = lane
    xnext = xp[(CH_ + lane) * NS_ + site];                // chunk 1
    float a0 = fc_b[0 * NH_ + lane];
    float a1 = fc_b[1 * NH_ + lane];
    float a7 = fc_b[7 * NH_ + lane];
#pragma unroll
    for (int g4 = 0; g4 < NG_ / 4; ++g4) {
      const float4 xv = xcq[g4];
      const float4 w0 = wq4[(0 * NH_ + lane) * (NG_ / 4) + g4];
      const float4 w1 = wq4[(1 * NH_ + lane) * (NG_ / 4) + g4];
      const float4 w7 = wq4[(7 * NH_ + lane) * (NG_ / 4) + g4];
      a0 = fmaf(xv.x, w0.x, a0); a0 = fmaf(xv.y, w0.y, a0);
      a0 = fmaf(xv.z, w0.z, a0); a0 = fmaf(xv.w, w0.w, a0);
      a1 = fmaf(xv.x, w1.x, a1); a1 = fmaf(xv.y, w1.y, a1);
      a1 = fmaf(xv.z, w1.z, a1); a1 = fmaf(xv.w, w1.w, a1);
      a7 = fmaf(xv.x, w7.x, a7); a7 = fmaf(xv.y, w7.y, a7);
      a7 = fmaf(xv.z, w7.z, a7); a7 = fmaf(xv.w, w7.w, a7);
    }
    gm  = expf(a0) + 1.0f;
    nge = -2.0f * sigmoidf(a1);     // -ge
    gi  = sigmoidf(a7);
    mm  = compute_met(xcur);        // per-lane met for chunk 0 (lane = t)
  } else {
    // ---- H prologue: 5-row + q mini-GEMM, softmax, folded constants
    float a2 = fc_b[2 * NH_ + lane];
    float a3 = fc_b[3 * NH_ + lane];
    float a4 = fc_b[4 * NH_ + lane];
    float a5 = fc_b[5 * NH_ + lane];
    float a6 = fc_b[6 * NH_ + lane];
    float aq = fc_b[NW_ - 1];
#pragma unroll
    for (int g4 = 0; g4 < NG_ / 4; ++g4) {
      const float4 xv = xcq[g4];
      const float4 w2 = wq4[(2 * NH_ + lane) * (NG_ / 4) + g4];
      const float4 w3 = wq4[(3 * NH_ + lane) * (NG_ / 4) + g4];
      const float4 w4 = wq4[(4 * NH_ + lane) * (NG_ / 4) + g4];
      const float4 w5 = wq4[(5 * NH_ + lane) * (NG_ / 4) + g4];
      const float4 w6 = wq4[(6 * NH_ + lane) * (NG_ / 4) + g4];
      const float4 wq = wq4[(NW_ - 1) * (NG_ / 4) + g4];
      a2 = fmaf(xv.x, w2.x, a2); a2 = fmaf(xv.y, w2.y, a2);
      a2 = fmaf(xv.z, w2.z, a2); a2 = fmaf(xv.w, w2.w, a2);
      a3 = fmaf(xv.x, w3.x, a3); a3 = fmaf(xv.y, w3.y, a3);
      a3 = fmaf(xv.z, w3.z, a3); a3 = fmaf(xv.w, w3.w, a3);
      a4 = fmaf(xv.x, w4.x, a4); a4 = fmaf(xv.y, w4.y, a4);
      a4 = fmaf(xv.z, w4.z, a4); a4 = fmaf(xv.w, w4.w, a4);
      a5 = fmaf(xv.x, w5.x, a5); a5 = fmaf(xv.y, w5.y, a5);
      a5 = fmaf(xv.z, w5.z, a5); a5 = fmaf(xv.w, w5.w, a5);
      a6 = fmaf(xv.x, w6.x, a6); a6 = fmaf(xv.y, w6.y, a6);
      a6 = fmaf(xv.z, w6.z, a6); a6 = fmaf(xv.w, w6.w, a6);
      aq = fmaf(xv.x, wq.x, aq); aq = fmaf(xv.y, wq.y, aq);
      aq = fmaf(xv.z, wq.z, aq); aq = fmaf(xv.w, wq.w, aq);
    }
    const float go = sigmoidf(a2);
    gl = expf(a3 * 2.0f);
    float mx = a4;
#pragma unroll
    for (int sh = 32; sh >= 1; sh >>= 1) mx = fmaxf(mx, __shfl_xor(mx, sh, 64));
    const float ex = expf(a4 - mx);
    float sme = ex;
#pragma unroll
    for (int sh = 32; sh >= 1; sh >>= 1) sme += __shfl_xor(sme, sh, 64);
    ga = ex / sme;
    const float gb = sigmoidf(a5);
    const float kb = sigmoidf(a6) * 0.1f;
    qb   = fmaxf(aq, 0.0f) * (1.0f / NH_);
    mgo  = -go;
    kb1m = 1.0f - kb;
    gbgo = gb * go;
    c1 = ga * (go * (1.0f - gb) - 1.0f);  // y = ga*Hh + c1*M + c2*G
    c2 = ga * kb;
  }

  // ---- S: produce one 32-step phase of dSm into dsm[ph&1]
  auto produce = [&](int ph) {
    float* ob = &dsm[ph & 1][myv][0][lane];
    const int tb = (ph & 1) << 5;           // uniform: readlane takes SGPR idx
#pragma unroll
    for (int u = 0; u < PH_; ++u) {
      const float Ps = rdl(mm.x, tb + u);
      const float Pl = rdl(mm.y, tb + u);
      const float Tz = rdl(mm.z, tb + u);
      const float Ev = rdl(mm.w, tb + u);
      const float melt = Tz * gm;
      const float dd = S0 - melt;
      const float r  = fmaxf(dd, 0.0f);     // S0 - Sm
      const float Sm = S0 - r;              // min(S0, melt)
      const float d  = fmaf(Pl, gi, fmaf(Ev, nge, Sm));  // dSm
      S0 = r + Ps;
      ob[u * NH_] = d;
    }
  };

  // ---- H: one step of the H/G/y recurrence (10 VALU + 1 ds_write)
  auto hstep = [&](float d, float* ywaddr) {
    const float z  = H0 + d;
    const float Hh = fmaxf(z, 0.0f);                    // H
    const float M  = __builtin_amdgcn_fmed3f(z, 0.0f, gl);  // min(H, gl)
    H0 = fminf(fmaf(mgo, M, Hh), gl);                   // min(H - go*M, gl)
    G  = fmaf(kb1m, G, gbgo * M);                       // pre-drain G
    *ywaddr = fmaf(c2, G, fmaf(c1, M, ga * Hh));
  };

  // ---- H: consume one 32-step phase (8-ahead reg prefetch, no ptr swap)
  auto consume = [&](int ph) {
    const float* db = &dsm[ph & 1][myv][0][lane];
    float* ywp = &ytile[myv][lane + (((ph & 1) << 5) * YPAD_)];
    float dA[8], dB[8];
#pragma unroll
    for (int i = 0; i < 8; ++i) dA[i] = db[i * NH_];
#pragma unroll
    for (int i = 0; i < 8; ++i) dB[i] = db[(8 + i) * NH_];
#pragma unroll
    for (int u = 0; u < 8; ++u) hstep(dA[u], ywp + u * YPAD_);
#pragma unroll
    for (int i = 0; i < 8; ++i) dA[i] = db[(16 + i) * NH_];
#pragma unroll
    for (int u = 0; u < 8; ++u) hstep(dB[u], ywp + (8 + u) * YPAD_);
#pragma unroll
    for (int i = 0; i < 8; ++i) dB[i] = db[(24 + i) * NH_];
#pragma unroll
    for (int u = 0; u < 8; ++u) hstep(dA[u], ywp + (16 + u) * YPAD_);
#pragma unroll
    for (int u = 0; u < 8; ++u) hstep(dB[u], ywp + (24 + u) * YPAD_);
  };

  // ---- H: transposed per-chunk reduction (lane t' sums row t', bank-free)
  auto reduce_out = [&](int c) {
    const float* yrr = &ytile[myv][lane * YPAD_];
    float r0 = 0.f, r1 = 0.f, r2 = 0.f, r3 = 0.f;
#pragma unroll
    for (int h2 = 0; h2 < CH_; h2 += 4) {
      r0 += yrr[h2 + 0];
      r1 += yrr[h2 + 1];
      r2 += yrr[h2 + 2];
      r3 += yrr[h2 + 3];
    }
    const int t_out = c * CH_ + lane;
    if (t_out < NT_) out[t_out * NS_ + site] = ((r0 + r1) + (r2 + r3)) + qb;
  };

  // ---- pipelined slots: S produces phase s while H consumes phase s-1
  if (isS) produce(0);
  __syncthreads();

#pragma unroll 1
  for (int s = 1; s < 12; ++s) {
    if (isS) {
      produce(s);
      if ((s & 1) && s < 11) {
        mm = compute_met(xnext);                   // advance to chunk (s>>1)+1
        int t2 = ((s >> 1) + 2) * CH_ + lane;      // fetch chunk (s>>1)+2
        if (t2 > NT_ - 1) t2 = NT_ - 1;
        xnext = xp[t2 * NS_ + site];
      }
    } else {
      consume(s - 1);
      if ((s - 1) & 1) reduce_out((s - 1) >> 1);   // chunk done -> reduce+store
    }
    __syncthreads();
  }
  if (!isS) { consume(11); reduce_out(5); }        // drain slot (no barrier)
}

extern "C" void kernel_launch(void* const* d_in, const int* in_sizes, int n_in,
                              void* d_out, int out_size, void* d_ws, size_t ws_size,
                              hipStream_t stream) {
  const float* x    = (const float*)d_in[0];
  const float* xc   = (const float*)d_in[1];
  const float* fc_w = (const float*)d_in[2];
  const float* fc_b = (const float*)d_in[3];
  float* out = (float*)d_out;

  // 1024 sites, 4 sites/block with an S-wave + H-wave each -> 512 threads,
  // 256 blocks, 129 KB LDS -> 1 block/CU, 2 waves/SIMD (1 producer + 1
  // consumer). Per-wave instruction stream is ~halved vs the fused kernel.
  hipLaunchKernelGGL(waternet_scan, dim3(NS_ / 4), dim3(512), 0, stream,
                     x, xc, fc_w, fc_b, out);
}